// Round 4
// baseline (861.822 us; speedup 1.0000x reference)
//
#include <hip/hip_runtime.h>

typedef unsigned char u8;

#define TT 1024
#define BB 512
#define LL 50
#define STOPI 48
#define STARTI 49
#define NEGV -10000.0f
#define NINF -3.4e38f
#define PSTR 1028   // bwd LDS row stride in bytes; 257 dwords, 257%32==1 -> banks spread

__device__ __forceinline__ float f3(float a, float b, float c) {
    return fmaxf(fmaxf(a, b), c);   // -> v_max3_f32
}

// ws layout:
//   [0, 2048)             : int idx[512]
//   [4096, 4096+B*50*T)   : u8 ptr[B][50][T]  backpointers, [label][time]

// One wave per batch, no barriers. vit broadcast through LDS uniform-address
// reads (DS pipe co-issues with VALU; no readlane->SGPR hazard). Exact argmax:
// max3 value tree + equality-scan index recovery (first-index preserved).
__global__ __launch_bounds__(64) void viterbi_fwd(
    const float* __restrict__ feats, const int* __restrict__ lens,
    const float* __restrict__ trans, float* __restrict__ out_scores,
    int* __restrict__ idx_ws, u8* __restrict__ ptr_ws)
{
    const int b    = blockIdx.x;
    const int lane = threadIdx.x;                    // lane == 'to' label
    const int row  = (lane < LL) ? lane : (LL - 1);  // clamp for OOB-safe setup

    float trr[LL];
#pragma unroll
    for (int j = 0; j < LL; ++j) trr[j] = trans[row * LL + j];
    const float tr_stop = trans[STOPI * LL + row];

    const int len = lens[b];
    const int nchunks = (len + 15) >> 4;

    __shared__ __align__(16) float featbuf[800];   // 16 rows x 50 floats
    __shared__ float vbuf[64];                     // vit broadcast buffer

    float vit = (lane == STARTI) ? 0.0f : NEGV;
    vbuf[lane] = vit;                              // in-order DS, single wave

    const float* fb = feats + (size_t)b * (TT * LL);
    u8* pt = ptr_ws + (size_t)b * (TT * LL) + (size_t)row * TT;  // [to][t]

    // prefetch chunk 0 into registers (4 x float4/lane covers 200 float4)
    float4 nf0, nf1, nf2, nf3;
    {
        const float4* s4 = (const float4*)fb;
        const int i3 = (lane + 192 > 199) ? 199 : lane + 192;
        nf0 = s4[lane]; nf1 = s4[lane + 64]; nf2 = s4[lane + 128]; nf3 = s4[i3];
    }

    // exact max + first-index argmax over the 50 broadcast scores
    auto stepcore = [&](float& M, int& I) {
        float s[LL];
#pragma unroll
        for (int j = 0; j < LL; ++j) s[j] = vbuf[j] + trr[j];   // ds broadcast + add

        // group maxima: [0,13) [13,26) [26,39) [39,50)   (25 max ops, exact)
        float g0, g1, g2, g3;
        {
            float a0 = f3(s[0], s[1], s[2]),  a1 = f3(s[3], s[4], s[5]);
            float a2 = f3(s[6], s[7], s[8]),  a3 = f3(s[9], s[10], s[11]);
            g0 = f3(f3(a0, a1, a2), a3, s[12]);
        }
        {
            float a0 = f3(s[13], s[14], s[15]), a1 = f3(s[16], s[17], s[18]);
            float a2 = f3(s[19], s[20], s[21]), a3 = f3(s[22], s[23], s[24]);
            g1 = f3(f3(a0, a1, a2), a3, s[25]);
        }
        {
            float a0 = f3(s[26], s[27], s[28]), a1 = f3(s[29], s[30], s[31]);
            float a2 = f3(s[32], s[33], s[34]), a3 = f3(s[35], s[36], s[37]);
            g2 = f3(f3(a0, a1, a2), a3, s[38]);
        }
        {
            float a0 = f3(s[39], s[40], s[41]), a1 = f3(s[42], s[43], s[44]);
            float a2 = f3(s[45], s[46], s[47]);
            g3 = f3(f3(a0, a1, a2), s[48], s[49]);
        }
        M = fmaxf(f3(g0, g1, g2), g3);

        // index recovery: descending eq-scans (4 parallel chains), then
        // first-group-wins merge -> global first-index argmax, exact.
        int i0 = 0, i1 = 13, i2 = 26, i3v = 39;
#pragma unroll
        for (int j = 12; j >= 0; --j)  i0  = (s[j] == M) ? j : i0;
#pragma unroll
        for (int j = 25; j >= 13; --j) i1  = (s[j] == M) ? j : i1;
#pragma unroll
        for (int j = 38; j >= 26; --j) i2  = (s[j] == M) ? j : i2;
#pragma unroll
        for (int j = 49; j >= 39; --j) i3v = (s[j] == M) ? j : i3v;
        int Iv = i3v;
        Iv = (g2 == M) ? i2 : Iv;
        Iv = (g1 == M) ? i1 : Iv;
        Iv = (g0 == M) ? i0 : Iv;
        I = Iv;
    };

    unsigned pk = 0;
    for (int c = 0; c < nchunks; ++c) {
        // stage chunk c (prefetched regs -> LDS); in-order DS, no barrier
        float4* f4 = (float4*)featbuf;
        {
            const int i3 = (lane + 192 > 199) ? 199 : lane + 192;
            f4[lane] = nf0; f4[lane + 64] = nf1; f4[lane + 128] = nf2; f4[i3] = nf3;
        }
        // prefetch chunk c+1 (vmcnt waited ~16 steps later, hidden)
        {
            const int cn = (c + 1 > 63) ? 63 : c + 1;
            const float4* s4 = (const float4*)(fb + cn * 800);
            const int i3 = (lane + 192 > 199) ? 199 : lane + 192;
            nf0 = s4[lane]; nf1 = s4[lane + 64]; nf2 = s4[lane + 128]; nf3 = s4[i3];
        }

        for (int i = 0; i < 16; ++i) {
            const int t = (c << 4) + i;
            const float f = featbuf[i * 50 + lane];   // issued early, used late

            float M; int I;
            stepcore(M, I);

            pk = (pk >> 8) | ((unsigned)I << 24);
            if ((t & 3) == 3 && lane < LL)
                *(unsigned*)(pt + t - 3) = pk;        // fire-and-forget

            if (t < len) {                            // wave-uniform
                float nv = M + f;
                if (t == len - 1) nv += tr_stop;
                vit = nv;
                vbuf[lane] = vit;                     // feed next step's broadcast
            }
        }
    }

    // frozen row for t >= nchunks*16 (vit frozen, ptr row constant)
    {
        float M; int I;
        stepcore(M, I);
        const unsigned pat = (unsigned)I * 0x01010101u;
        uint4 qv; qv.x = pat; qv.y = pat; qv.z = pat; qv.w = pat;
        if (lane < LL)
            for (int c2 = nchunks; c2 < 64; ++c2)
                *(uint4*)(pt + (c2 << 4)) = qv;
    }

    // final score / first-index argmax over vit[0..49] (uniform, once)
    {
        float m = NINF; int mi = 0;
#pragma unroll
        for (int j = 0; j < LL; ++j) {
            float v = vbuf[j];
            if (v > m) { m = v; mi = j; }
        }
        if (lane == 0) { out_scores[b] = m; idx_ws[b] = mi; }
    }
}

// Backtrack with chunked pointer-jumping: 32 chunks x 32 steps.
// LDS rows padded to PSTR=1028 B so per-lane row index spreads across banks.
__global__ __launch_bounds__(64) void viterbi_bwd(
    const int* __restrict__ idx_ws, const u8* __restrict__ ptr_ws,
    float* __restrict__ out_paths)
{
    const int b = blockIdx.x;
    const int lane = threadIdx.x;

    __shared__ u8 lptr[LL * PSTR];   // 51400 B, row stride 1028
    __shared__ u8 maps[32 * LL];
    __shared__ int entries[33];

    // stage: coalesced u32 global loads, strided u32 LDS writes
    {
        const unsigned* src = (const unsigned*)(ptr_ws + (size_t)b * TT * LL);
        for (int w = lane; w < (TT * LL) / 4; w += 64) {
            int r = w >> 8;              // 256 dwords per 1024B row
            int col = w & 255;
            *(unsigned*)&lptr[r * PSTR + (col << 2)] = src[w];
        }
    }
    __syncthreads();

    // phase 1: all 1600 (chunk, entry) walks; 25 independent chains per lane
    {
        int st[25], tt[25], cidx[25];
#pragma unroll
        for (int k = 0; k < 25; ++k) {
            int w = k * 64 + lane;       // 0..1599
            int c = w / 50;
            int l = w - c * 50;
            st[k] = l;
            tt[k] = c * 32 + 31;
            cidx[k] = c * 50 + l;
        }
        for (int j = 0; j < 32; ++j) {
#pragma unroll
            for (int k = 0; k < 25; ++k) {
                st[k] = lptr[st[k] * PSTR + tt[k]];
                tt[k] -= 1;
            }
        }
#pragma unroll
        for (int k = 0; k < 25; ++k) maps[cidx[k]] = (u8)st[k];
    }
    __syncthreads();

    const int idx = idx_ws[b];

    // phase 2: compose chunk maps sequentially
    if (lane == 0) {
        int i = idx;
        for (int c = 31; c >= 0; --c) {
            entries[c + 1] = i;
            i = maps[c * 50 + i];
        }
        entries[0] = i;
    }
    __syncthreads();

    // phase 3: re-walk all 32 chunks in parallel, writing the path
    float* po = out_paths + (size_t)b * TT;
    if (lane < 32) {
        const int c = lane;
        int s = entries[c + 1];
        for (int j = 0; j < 32; ++j) {
            int t = c * 32 + 31 - j;
            int ni = lptr[s * PSTR + t];
            if (t > 0) po[t - 1] = (float)ni;   // paths[t-1] = back_seq[t]
            s = ni;
        }
    }
    if (lane == 0) po[TT - 1] = (float)idx;     // paths[T-1] = argmax(vit)
}

extern "C" void kernel_launch(void* const* d_in, const int* in_sizes, int n_in,
                              void* d_out, int out_size, void* d_ws, size_t ws_size,
                              hipStream_t stream) {
    const float* feats = (const float*)d_in[0];
    const int*   lens  = (const int*)d_in[1];
    const float* trans = (const float*)d_in[2];

    float* scores = (float*)d_out;          // [512]
    float* paths  = scores + BB;            // [512*1024] ints as floats

    int* idx_ws = (int*)d_ws;
    u8*  ptr_ws = (u8*)d_ws + 4096;

    viterbi_fwd<<<BB, 64, 0, stream>>>(feats, lens, trans, scores, idx_ws, ptr_ws);
    viterbi_bwd<<<BB, 64, 0, stream>>>(idx_ws, ptr_ws, paths);
}